// Round 5
// baseline (41.585 us; speedup 1.0000x reference)
//
#include <hip/hip_runtime.h>

#define KDIM 256
#define DWIN 20
#define NOBS 8192
#define TAU  20
#define TROWS (NOBS - TAU)          // 8172
#define KTOT  (DWIN * KDIM)         // 5120
#define KSTEPS (KTOT / 32)          // 160
#define QSTEPS (KSTEPS / 4)         // 40 per wave (K-quarter)

#define BM 64
#define NBLK_M ((TROWS + BM - 1) / BM)   // 128
#define NBLK   (NBLK_M * 4)              // 512

#define AROWS 83                     // 64 + DWIN - 1
#define APAD  280                    // 560B row stride (2-way bank alias = free)

// dynamic LDS: A panel (46,480B) overlaps the 64KB partial-C exchange region
#define PC_BYTES  65536
#define SRED_OFF  PC_BYTES
#define DYN_TOTAL (PC_BYTES + 64)

typedef __bf16 bf16x8 __attribute__((ext_vector_type(8)));
typedef float  f32x4  __attribute__((ext_vector_type(4)));
typedef unsigned short u16x8 __attribute__((ext_vector_type(8)));

// ws layout (bytes):
#define WS_BF    0u
#define WS_PART  (KSTEPS * 16u * 64u * 8u * 2u)   // 2,621,440
#define WS_NEED  (WS_PART + NBLK * 8u)

__device__ __forceinline__ unsigned short f2bf(float f) {
    unsigned int u = __float_as_uint(f);
    unsigned int r = (u + 0x7fffu + ((u >> 16) & 1u)) >> 16;   // RN-even
    return (unsigned short)r;
}

// ---- prep: beta1 -> fragment-major B (layout verified R2-R4), 8 elem/thread ----
// Bf[((ks*16 + nt)*64 + lane)*8 + j] = bf16(B[k][n]),
//   k = ks*32 + (lane>>4)*8 + j,  n = nt*16 + (lane&15),
//   B[k][n] = beta1[n][b][a], a = k>>8, b = k&255
__global__ void prep_bfrag_kernel(const float* __restrict__ beta1,
                                  unsigned short* __restrict__ Bf)
{
    const int base = (blockIdx.x * 256 + threadIdx.x) * 8;   // [0, 1310720)
    const int lane = (base >> 3) & 63;
    const int nt   = (base >> 9) & 15;
    const int ks   = base >> 13;
    const int n     = nt * 16 + (lane & 15);
    const int kbase = ks * 32 + (lane >> 4) * 8;
    const float* __restrict__ bn = beta1 + (size_t)n * KTOT;
    u16x8 r;
#pragma unroll
    for (int j = 0; j < 8; ++j) {
        int k = kbase + j;
        r[j] = f2bf(bn[(k & 255) * DWIN + (k >> 8)]);
    }
    *(u16x8*)&Bf[base] = r;
}

extern __shared__ char dynlds[];

// ---- main GEMM: block 64x64 output, 4 waves K-split, barrier-free loop,
//      B fed global->register (no LDS round-trip) ----
__global__ __launch_bounds__(256, 2)
void gemm_kernel(const float* __restrict__ obs,
                 const float* __restrict__ beta0,
                 const unsigned short* __restrict__ Bf,
                 float* __restrict__ out,
                 double* __restrict__ partials)
{
    const int tid  = threadIdx.x;
    const int lane = tid & 63;
    const int w    = tid >> 6;     // wave id: owns K-quarter [40w, 40w+40)
    const int g = lane >> 4;
    const int q = lane & 15;
    const int nb = blockIdx.x & 3;
    const int mb = blockIdx.x >> 2;
    const int i0 = mb * BM;

    unsigned short* ldsA = (unsigned short*)dynlds;

    // B slice pointer: phase s lives at bbase + s*16384, t-tile at +t*1024
    const char* bbase = (const char*)Bf + (size_t)(4 * nb) * 1024
                      + (size_t)(40 * w) * 16384 + (size_t)lane * 16;

    // prefetch B(s=0) into registers before A staging (hides under LDS fill)
    bf16x8 bA[4], bB[4];
#pragma unroll
    for (int t = 0; t < 4; ++t)
        bA[t] = *(const bf16x8*)(bbase + t * 1024);

    // --- stage A panel: rows i0..i0+82 (clamped), fused fp32->bf16 ---
    for (int idx = tid; idx < AROWS * 64; idx += 256) {
        int row = idx >> 6, c4 = idx & 63;
        int grow = min(i0 + row, NOBS - 1);
        float4 v = ((const float4*)obs)[(size_t)grow * 64 + c4];
        ushort4 r;
        r.x = f2bf(v.x); r.y = f2bf(v.y); r.z = f2bf(v.z); r.w = f2bf(v.w);
        *(ushort4*)&ldsA[row * APAD + c4 * 4] = r;
    }
    __syncthreads();

    f32x4 acc[4][4];
#pragma unroll
    for (int m = 0; m < 4; ++m)
#pragma unroll
        for (int t = 0; t < 4; ++t)
            acc[m][t] = (f32x4){0.f, 0.f, 0.f, 0.f};

#define COMPUTE(s, breg)                                                         \
    {                                                                            \
        const int _ks = 40 * w + (s);                                            \
        const int _acol = ((_ks & 7) * 32 + g * 8);                              \
        const int _aro  = (_ks >> 3);                                            \
        bf16x8 _af[4];                                                           \
        _Pragma("unroll")                                                        \
        for (int m = 0; m < 4; ++m)                                              \
            _af[m] = *(const bf16x8*)&ldsA[(m * 16 + q + _aro) * APAD + _acol];  \
        _Pragma("unroll")                                                        \
        for (int t = 0; t < 4; ++t)                                              \
            _Pragma("unroll")                                                    \
            for (int m = 0; m < 4; ++m)                                          \
                acc[m][t] = __builtin_amdgcn_mfma_f32_16x16x32_bf16(_af[m], (breg)[t], acc[m][t], 0, 0, 0); \
    }

#pragma unroll 1
    for (int s = 0; s < QSTEPS; s += 2) {
        // prefetch s+1 while computing s
#pragma unroll
        for (int t = 0; t < 4; ++t)
            bB[t] = *(const bf16x8*)(bbase + (size_t)(s + 1) * 16384 + t * 1024);
        COMPUTE(s, bA)
        // prefetch s+2 while computing s+1
        if (s + 2 < QSTEPS) {
#pragma unroll
            for (int t = 0; t < 4; ++t)
                bA[t] = *(const bf16x8*)(bbase + (size_t)(s + 2) * 16384 + t * 1024);
        }
        COMPUTE(s + 1, bB)
    }

    // --- exchange partial C through LDS (reuses A region) ---
    __syncthreads();
    f32x4* pc = (f32x4*)dynlds;        // 4096 x 16B = 64KB
#pragma unroll
    for (int m = 0; m < 4; ++m)
#pragma unroll
        for (int t = 0; t < 4; ++t)
            pc[((w * 16 + m * 4 + t) << 6) + lane] = acc[m][t];
    __syncthreads();

    // wave w reduces band m=w, fused epilogue
    double part = 0.0;
#pragma unroll
    for (int t = 0; t < 4; ++t) {
        f32x4 sum = pc[((w * 4 + t) << 6) + lane];
#pragma unroll
        for (int wp = 1; wp < 4; ++wp)
            sum += pc[((wp * 16 + w * 4 + t) << 6) + lane];
        const int col = nb * 64 + t * 16 + q;
        const float b0v = beta0[col];
#pragma unroll
        for (int r = 0; r < 4; ++r) {
            const int row = i0 + w * 16 + 4 * g + r;   // C/D: row=(lane>>4)*4+reg
            if (row < TROWS) {
                float lam = sum[r] + b0v;
                out[1 + (size_t)row * KDIM + col] = lam;
                float o = obs[(size_t)(row + TAU) * KDIM + col];
                part += (double)o * (double)__logf(lam) - (double)lam;
            }
        }
    }

#pragma unroll
    for (int off = 32; off > 0; off >>= 1) part += __shfl_down(part, off, 64);
    double* sred = (double*)(dynlds + SRED_OFF);
    if (lane == 0) sred[w] = part;
    __syncthreads();
    if (tid == 0) partials[blockIdx.x] = sred[0] + sred[1] + sred[2] + sred[3];
}

__global__ void reduce_final_kernel(const double* __restrict__ partials,
                                    float* __restrict__ out, int n)
{
    __shared__ double sr[256];
    double v = 0.0;
    for (int i = threadIdx.x; i < n; i += 256) v += partials[i];
    sr[threadIdx.x] = v;
    __syncthreads();
    for (int off = 128; off > 0; off >>= 1) {
        if (threadIdx.x < off) sr[threadIdx.x] += sr[threadIdx.x + off];
        __syncthreads();
    }
    if (threadIdx.x == 0) out[0] = (float)sr[0];
}

// ================= fallback fp32 path (R1, proven) =================
#define BM_OLD 16
#define NBLK_OLD ((TROWS + BM_OLD - 1) / BM_OLD)   // 511

__global__ __launch_bounds__(KDIM, 2)
void old_lam_kernel(const float* __restrict__ obs,
                    const float* __restrict__ beta0,
                    const float* __restrict__ beta1,
                    float* __restrict__ out,
                    double* __restrict__ partials)
{
    const int k  = threadIdx.x;
    const int i0 = blockIdx.x * BM_OLD;
    const int nr = min(BM_OLD, TROWS - i0);
    const int smax = nr + DWIN - 1;

    float acc[BM_OLD];
#pragma unroll
    for (int r = 0; r < BM_OLD; ++r) acc[r] = 0.f;

    const float* __restrict__ b1k = beta1 + (size_t)k * (KDIM * DWIN);

    for (int b = 0; b < KDIM; ++b) {
        float br[DWIN];
        const float4* qd = (const float4*)(b1k + b * DWIN);
#pragma unroll
        for (int v = 0; v < DWIN / 4; ++v) {
            float4 t = qd[v];
            br[4*v+0] = t.x; br[4*v+1] = t.y; br[4*v+2] = t.z; br[4*v+3] = t.w;
        }
        float wv[BM_OLD + DWIN - 1];
#pragma unroll
        for (int s = 0; s < BM_OLD + DWIN - 1; ++s)
            wv[s] = (s < smax) ? obs[(size_t)(i0 + s) * KDIM + b] : 0.f;
#pragma unroll
        for (int r = 0; r < BM_OLD; ++r)
#pragma unroll
            for (int a = 0; a < DWIN; ++a)
                acc[r] = fmaf(wv[r + a], br[a], acc[r]);
    }

    const float b0 = beta0[k];
    double part = 0.0;
    for (int r = 0; r < nr; ++r) {
        float lam = acc[r] + b0;
        out[1 + (size_t)(i0 + r) * KDIM + k] = lam;
        float o = obs[(size_t)(i0 + r + TAU) * KDIM + k];
        part += (double)(o * logf(lam) - lam);
    }

    __shared__ double sred2[KDIM];
    sred2[k] = part;
    __syncthreads();
    for (int off = KDIM / 2; off > 0; off >>= 1) {
        if (k < off) sred2[k] += sred2[k + off];
        __syncthreads();
    }
    if (k == 0) partials[blockIdx.x] = sred2[0];
}
// ===================================================================

extern "C" void kernel_launch(void* const* d_in, const int* in_sizes, int n_in,
                              void* d_out, int out_size, void* d_ws, size_t ws_size,
                              hipStream_t stream)
{
    const float* obs   = (const float*)d_in[0];
    const float* beta0 = (const float*)d_in[1];
    const float* beta1 = (const float*)d_in[2];
    float* out = (float*)d_out;

    if (ws_size >= (size_t)WS_NEED) {
        unsigned short* Bf = (unsigned short*)((char*)d_ws + WS_BF);
        double* partials   = (double*)((char*)d_ws + WS_PART);

        (void)hipFuncSetAttribute(reinterpret_cast<const void*>(gemm_kernel),
                                  hipFuncAttributeMaxDynamicSharedMemorySize,
                                  DYN_TOTAL);

        hipLaunchKernelGGL(prep_bfrag_kernel, dim3(640), dim3(256), 0, stream, beta1, Bf);
        hipLaunchKernelGGL(gemm_kernel, dim3(NBLK), dim3(256), DYN_TOTAL, stream,
                           obs, beta0, Bf, out, partials);
        hipLaunchKernelGGL(reduce_final_kernel, dim3(1), dim3(256), 0, stream,
                           partials, out, NBLK);
    } else {
        double* partials = (double*)d_ws;
        hipLaunchKernelGGL(old_lam_kernel, dim3(NBLK_OLD), dim3(KDIM), 0, stream,
                           obs, beta0, beta1, out, partials);
        hipLaunchKernelGGL(reduce_final_kernel, dim3(1), dim3(256), 0, stream,
                           partials, out, NBLK_OLD);
    }
}